// Round 1
// baseline (609.312 us; speedup 1.0000x reference)
//
#include <hip/hip_runtime.h>
#include <math.h>

// Problem constants
#define NN 4096
#define DD 256
#define HH 8
#define HDIM 32
constexpr float SCALE = 0.17677669529663687f; // 1/sqrt(32)

// ---------------------------------------------------------------------------
// Generic GEMM: C[M,NOUT] = A[M,256] @ W[256,NOUT] + bias
// block = 256 threads, 8 rows of A per block, CPT = NOUT/256 cols per thread.
// A rows staged in LDS (broadcast reads, conflict-free). W loads coalesced.
// ---------------------------------------------------------------------------
template <int NOUT, int CPT>
__global__ __launch_bounds__(256) void gemm_k256(const float* __restrict__ A,
                                                 const float* __restrict__ W,
                                                 const float* __restrict__ bias,
                                                 float* __restrict__ C) {
    const int tx = threadIdx.x;
    const int row0 = blockIdx.x * 8;

    __shared__ float xs[8][256];
    {
        const float4* A4 = (const float4*)(A + (size_t)row0 * 256);
        float4* xs4 = (float4*)&xs[0][0];
        xs4[tx] = A4[tx];
        xs4[tx + 256] = A4[tx + 256];
    }
    __syncthreads();

    float acc[8][CPT];
#pragma unroll
    for (int r = 0; r < 8; ++r)
#pragma unroll
        for (int c = 0; c < CPT; ++c) acc[r][c] = 0.f;

    const float* Wt = W + tx;
#pragma unroll 4
    for (int k = 0; k < 256; ++k) {
        float w[CPT];
#pragma unroll
        for (int c = 0; c < CPT; ++c) w[c] = Wt[(size_t)k * NOUT + c * 256];
#pragma unroll
        for (int r = 0; r < 8; ++r) {
            const float xv = xs[r][k];
#pragma unroll
            for (int c = 0; c < CPT; ++c) acc[r][c] += xv * w[c];
        }
    }

#pragma unroll
    for (int c = 0; c < CPT; ++c) {
        const float b = bias[tx + c * 256];
#pragma unroll
        for (int r = 0; r < 8; ++r) {
            C[(size_t)(row0 + r) * NOUT + tx + c * 256] = acc[r][c] + b;
        }
    }
}

// ---------------------------------------------------------------------------
// pe projection, stored transposed: ppT[h*N + n] = pe[n,:] @ Wpe[:,h] + bpe[h]
// ---------------------------------------------------------------------------
__global__ __launch_bounds__(256) void pe_proj_kernel(const float* __restrict__ pe,
                                                      const float* __restrict__ Wpe,
                                                      const float* __restrict__ bpe,
                                                      float* __restrict__ ppT) {
    const int idx = blockIdx.x * 256 + threadIdx.x; // 0..32767
    const int h = idx >> 12;
    const int n = idx & 4095;
    float acc = bpe[h];
#pragma unroll
    for (int k = 0; k < 16; ++k) acc += pe[n * 16 + k] * Wpe[k * 8 + h];
    ppT[h * NN + n] = acc;
}

// ---------------------------------------------------------------------------
// Flash attention (fp32 vector version, baseline).
// grid = (N/64, H); block = 256 threads = 4 waves.
// Each wave owns 64 queries (lane = query) and processes key tiles
// kt = wave, wave+4, ... (64-key tiles), producing per-wave online-softmax
// partials (m, l, o[32]) that are merged through LDS at the end.
// Score: s = SCALE * q.k - pp[key]  (pp[query] term cancels in softmax).
// ---------------------------------------------------------------------------
__global__ __launch_bounds__(256) void attn_kernel(const float* __restrict__ qkv,
                                                   const float* __restrict__ ppT,
                                                   float* __restrict__ attnout) {
    const int tx = threadIdx.x;
    const int wave = tx >> 6;
    const int lane = tx & 63;
    const int qb = blockIdx.x;  // 0..63
    const int h = blockIdx.y;   // 0..7
    const int nq = qb * 64 + lane;

    __shared__ float kt[4][64 * 32]; // per-wave K tile
    __shared__ float vt[4][64 * 32]; // per-wave V tile
    __shared__ float ppt[4][64];
    __shared__ float mls[4][64][2];

    // load q (scaled)
    float4 q4[8];
    {
        const float4* qp = (const float4*)(qkv + (size_t)nq * 768 + h * 32);
#pragma unroll
        for (int c = 0; c < 8; ++c) {
            float4 t = qp[c];
            t.x *= SCALE; t.y *= SCALE; t.z *= SCALE; t.w *= SCALE;
            q4[c] = t;
        }
    }

    float m = -1e30f, l = 0.f;
    float4 o4[8];
#pragma unroll
    for (int c = 0; c < 8; ++c) { o4[c].x = 0.f; o4[c].y = 0.f; o4[c].z = 0.f; o4[c].w = 0.f; }

    float* ktw = &kt[wave][0];
    float* vtw = &vt[wave][0];

    for (int kti = wave; kti < 64; kti += 4) {
        const int key0 = kti * 64;
        // cooperative (within-wave) tile load: 64 keys x 32 floats, float4s
        {
            float4* kd = (float4*)ktw;
            float4* vd = (float4*)vtw;
#pragma unroll
            for (int c = 0; c < 8; ++c) {
                const int f = c * 64 + lane;       // 0..511
                const int j = f >> 3;              // key within tile
                const int d = (f & 7) * 4;         // dim offset
                const size_t gb = (size_t)(key0 + j) * 768 + h * 32 + d;
                kd[f] = *(const float4*)(qkv + gb + 256);
                vd[f] = *(const float4*)(qkv + gb + 512);
            }
            ppt[wave][lane] = ppT[h * NN + key0 + lane];
        }
        // wave-private LDS; HW lgkmcnt ordering within the wave suffices.

#pragma unroll 1
        for (int jj0 = 0; jj0 < 64; jj0 += 16) {
            float s[16];
#pragma unroll
            for (int jj = 0; jj < 16; ++jj) {
                const float4* kr = (const float4*)(ktw + (jj0 + jj) * 32);
                float a0 = 0.f, a1 = 0.f, a2 = 0.f, a3 = 0.f;
#pragma unroll
                for (int c = 0; c < 8; ++c) {
                    const float4 kv = kr[c];
                    a0 += q4[c].x * kv.x;
                    a1 += q4[c].y * kv.y;
                    a2 += q4[c].z * kv.z;
                    a3 += q4[c].w * kv.w;
                }
                s[jj] = (a0 + a1) + (a2 + a3) - ppt[wave][jj0 + jj];
            }
            float cmax = s[0];
#pragma unroll
            for (int jj = 1; jj < 16; ++jj) cmax = fmaxf(cmax, s[jj]);
            const float mnew = fmaxf(m, cmax);
            const float alpha = __expf(m - mnew);
            l *= alpha;
#pragma unroll
            for (int c = 0; c < 8; ++c) {
                o4[c].x *= alpha; o4[c].y *= alpha; o4[c].z *= alpha; o4[c].w *= alpha;
            }
            m = mnew;
#pragma unroll
            for (int jj = 0; jj < 16; ++jj) {
                const float p = __expf(s[jj] - mnew);
                l += p;
                const float4* vr = (const float4*)(vtw + (jj0 + jj) * 32);
#pragma unroll
                for (int c = 0; c < 8; ++c) {
                    const float4 vv = vr[c];
                    o4[c].x += p * vv.x;
                    o4[c].y += p * vv.y;
                    o4[c].z += p * vv.z;
                    o4[c].w += p * vv.w;
                }
            }
        }
    }

    // merge the 4 per-wave partials through LDS
    __syncthreads();
    {
        float* opart = &kt[0][0]; // reuse: [4][64][32]
        float4* dst = (float4*)(opart + (size_t)(wave * 64 + lane) * 32);
#pragma unroll
        for (int c = 0; c < 8; ++c) dst[c] = o4[c];
        mls[wave][lane][0] = m;
        mls[wave][lane][1] = l;
    }
    __syncthreads();

    if (tx < 64) {
        const float m0 = mls[0][lane][0], l0 = mls[0][lane][1];
        const float m1 = mls[1][lane][0], l1 = mls[1][lane][1];
        const float m2 = mls[2][lane][0], l2 = mls[2][lane][1];
        const float m3 = mls[3][lane][0], l3 = mls[3][lane][1];
        const float M = fmaxf(fmaxf(m0, m1), fmaxf(m2, m3));
        const float w0 = __expf(m0 - M), w1 = __expf(m1 - M);
        const float w2 = __expf(m2 - M), w3 = __expf(m3 - M);
        const float L = w0 * l0 + w1 * l1 + w2 * l2 + w3 * l3;
        const float inv = 1.f / L;

        const float* opart = &kt[0][0];
        float4* dst = (float4*)(attnout + (size_t)(qb * 64 + lane) * 256 + h * 32);
#pragma unroll
        for (int c = 0; c < 8; ++c) {
            const float4 p0 = ((const float4*)(opart + (size_t)(0 * 64 + lane) * 32))[c];
            const float4 p1 = ((const float4*)(opart + (size_t)(1 * 64 + lane) * 32))[c];
            const float4 p2 = ((const float4*)(opart + (size_t)(2 * 64 + lane) * 32))[c];
            const float4 p3 = ((const float4*)(opart + (size_t)(3 * 64 + lane) * 32))[c];
            float4 r;
            r.x = (w0 * p0.x + w1 * p1.x + w2 * p2.x + w3 * p3.x) * inv;
            r.y = (w0 * p0.y + w1 * p1.y + w2 * p2.y + w3 * p3.y) * inv;
            r.z = (w0 * p0.z + w1 * p1.z + w2 * p2.z + w3 * p3.z) * inv;
            r.w = (w0 * p0.w + w1 * p1.w + w2 * p2.w + w3 * p3.w) * inv;
            dst[c] = r;
        }
    }
}

// ---------------------------------------------------------------------------
extern "C" void kernel_launch(void* const* d_in, const int* in_sizes, int n_in,
                              void* d_out, int out_size, void* d_ws, size_t ws_size,
                              hipStream_t stream) {
    const float* x    = (const float*)d_in[0];
    const float* pe   = (const float*)d_in[1];
    const float* Wqkv = (const float*)d_in[2];
    const float* bqkv = (const float*)d_in[3];
    const float* Wpe  = (const float*)d_in[4];
    const float* bpe  = (const float*)d_in[5];
    const float* Wout = (const float*)d_in[6];
    const float* bout = (const float*)d_in[7];
    float* out = (float*)d_out;

    float* ws = (float*)d_ws;
    float* qkv     = ws;                          // 4096*768 = 3,145,728 floats
    float* ppT     = qkv + (size_t)NN * 768;      // 8*4096   = 32,768 floats
    float* attnout = ppT + (size_t)HH * NN;       // 4096*256 = 1,048,576 floats

    // 1) QKV projection
    gemm_k256<768, 3><<<NN / 8, 256, 0, stream>>>(x, Wqkv, bqkv, qkv);
    // 2) PE projection (transposed store)
    pe_proj_kernel<<<(HH * NN) / 256, 256, 0, stream>>>(pe, Wpe, bpe, ppT);
    // 3) Flash attention with folded PE bias
    attn_kernel<<<dim3(NN / 64, HH), 256, 0, stream>>>(qkv, ppT, attnout);
    // 4) Output projection
    gemm_k256<256, 1><<<NN / 8, 256, 0, stream>>>(attnout, Wout, bout, out);
}

// Round 2
// 206.343 us; speedup vs baseline: 2.9529x; 2.9529x over previous
//
#include <hip/hip_runtime.h>
#include <math.h>

#define NN 4096
#define HH 8
constexpr float SCALE = 0.17677669529663687f;   // 1/sqrt(32)
constexpr float LOG2E = 1.4426950408889634f;
constexpr float SC2   = SCALE * LOG2E;          // score -> exp2 domain

typedef __bf16 bf16;
typedef __bf16 bf16x8 __attribute__((ext_vector_type(8)));
typedef __bf16 bf16x4 __attribute__((ext_vector_type(4)));
typedef float  f32x4  __attribute__((ext_vector_type(4)));

// ---------------------------------------------------------------------------
// GEMM: C[M,NOUT] = A[M,256] @ W[256,NOUT] + bias, output cast to OT.
// block=256, 8 rows/block. float4 LDS reads (4x fewer ds_read than round 1).
// ---------------------------------------------------------------------------
template <int NOUT, int CPT, typename OT>
__global__ __launch_bounds__(256) void gemm_k256(const float* __restrict__ A,
                                                 const float* __restrict__ W,
                                                 const float* __restrict__ bias,
                                                 OT* __restrict__ C) {
    const int tx = threadIdx.x;
    const int row0 = blockIdx.x * 8;

    __shared__ __align__(16) float xs[8][256];
    {
        const float4* A4 = (const float4*)(A + (size_t)row0 * 256);
        float4* xs4 = (float4*)&xs[0][0];
        xs4[tx] = A4[tx];
        xs4[tx + 256] = A4[tx + 256];
    }
    __syncthreads();

    float acc[8][CPT];
#pragma unroll
    for (int r = 0; r < 8; ++r)
#pragma unroll
        for (int c = 0; c < CPT; ++c) acc[r][c] = 0.f;

    const float* Wt = W + tx;
    for (int k4 = 0; k4 < 64; ++k4) {
        float w[4][CPT];
#pragma unroll
        for (int kk = 0; kk < 4; ++kk)
#pragma unroll
            for (int c = 0; c < CPT; ++c)
                w[kk][c] = Wt[(size_t)(k4 * 4 + kk) * NOUT + c * 256];
#pragma unroll
        for (int r = 0; r < 8; ++r) {
            const float4 xv = *(const float4*)&xs[r][k4 * 4];
#pragma unroll
            for (int c = 0; c < CPT; ++c) {
                acc[r][c] = fmaf(xv.x, w[0][c], acc[r][c]);
                acc[r][c] = fmaf(xv.y, w[1][c], acc[r][c]);
                acc[r][c] = fmaf(xv.z, w[2][c], acc[r][c]);
                acc[r][c] = fmaf(xv.w, w[3][c], acc[r][c]);
            }
        }
    }

#pragma unroll
    for (int c = 0; c < CPT; ++c) {
        const float b = bias[tx + c * 256];
#pragma unroll
        for (int r = 0; r < 8; ++r)
            C[(size_t)(row0 + r) * NOUT + tx + c * 256] = (OT)(acc[r][c] + b);
    }
}

// ---------------------------------------------------------------------------
// pe projection, transposed + pre-scaled by log2(e):
// ppT[h*N + n] = (pe[n,:] @ Wpe[:,h] + bpe[h]) * LOG2E
// ---------------------------------------------------------------------------
__global__ __launch_bounds__(256) void pe_proj_kernel(const float* __restrict__ pe,
                                                      const float* __restrict__ Wpe,
                                                      const float* __restrict__ bpe,
                                                      float* __restrict__ ppT) {
    const int idx = blockIdx.x * 256 + threadIdx.x;
    const int h = idx >> 12;
    const int n = idx & 4095;
    float acc = bpe[h];
#pragma unroll
    for (int k = 0; k < 16; ++k) acc += pe[n * 16 + k] * Wpe[k * 8 + h];
    ppT[h * NN + n] = acc * LOG2E;
}

// ---------------------------------------------------------------------------
// Pre-transpose V into MFMA A-fragment order.
// Out chunk for (h, kt=key-tile, dt=d-half, kc=key-half): 64 lanes x 8 bf16:
//   lane l holds V[kt*64 + kc*32 + (l>>4)*8 + jj][dt*16 + (l&15)], jj=0..7
// stored flat at ((h*64+kt)*256 + (dt*2+kc)*64 + l) * 8 bf16.
// ---------------------------------------------------------------------------
__global__ __launch_bounds__(256) void vtrans_kernel(const bf16* __restrict__ qkvb,
                                                     bf16* __restrict__ vt) {
    const int t = threadIdx.x;
    const int kt = blockIdx.x, h = blockIdx.y;
    __shared__ __align__(16) bf16 vtile[64 * 32]; // [token][dim]
    {
        const int tok = kt * 64 + (t >> 2);
        const uint4 v = *(const uint4*)(qkvb + (size_t)tok * 768 + 512 + h * 32 + (t & 3) * 8);
        *(uint4*)&vtile[t * 8] = v;
    }
    __syncthreads();
    const int l = t & 63;
    const int kc = (t >> 6) & 1, dt = t >> 7;
    const int q = l >> 4, i = l & 15;
    bf16x8 o;
#pragma unroll
    for (int jj = 0; jj < 8; ++jj)
        o[jj] = vtile[(kc * 32 + q * 8 + jj) * 32 + dt * 16 + i];
    *(bf16x8*)(vt + ((size_t)(h * 64 + kt) * 256 + t) * 8) = o;
}

// ---------------------------------------------------------------------------
// MFMA flash attention. grid=(64 q-tiles, 8 heads), block=256 (4 waves).
// Wave w owns queries qb*64+w*16..+15 (Q = B-operand, resident in regs).
// Per 64-key tile: 4 QK^T mfma (S^T: row=key, col=query), exp2-domain online
// softmax, P->LDS (bf16, stride-72 rows), 4 PV mfma accumulating O^T.
// ---------------------------------------------------------------------------
__global__ __launch_bounds__(256) void attn_kernel(const bf16* __restrict__ qkvb,
                                                   const bf16* __restrict__ vtf,
                                                   const float* __restrict__ ppT,
                                                   float* __restrict__ attnout) {
    const int t = threadIdx.x;
    const int wave = t >> 6, lane = t & 63;
    const int quad = lane >> 4, i16 = lane & 15;
    const int qb = blockIdx.x, h = blockIdx.y;

    __shared__ __align__(16) bf16 Klds[64 * 32];   // [key][dim]
    __shared__ __align__(16) bf16 Vlds[4 * 512];   // frag-order chunks
    __shared__ __align__(16) bf16 Pt[4][16 * 72];  // per-wave P^T, stride 72
    __shared__ float pps[64];

    // Q fragment (B operand): lane holds Q[q0w + (lane&15)][quad*8 .. +7]
    const int q0w = qb * 64 + wave * 16;
    const bf16x8 qf = *(const bf16x8*)(qkvb + (size_t)(q0w + i16) * 768 + h * 32 + quad * 8);

    f32x4 o0 = {0.f, 0.f, 0.f, 0.f}, o1 = {0.f, 0.f, 0.f, 0.f};
    float m = -1e30f, l = 0.f;

    const bf16* kstage = qkvb + (size_t)(t >> 2) * 768 + 256 + h * 32 + (t & 3) * 8;
    const bf16* vstage = vtf + (size_t)h * 64 * 2048 + t * 8;
    const float* ppg = ppT + h * NN + t;
    bf16* ptw = &Pt[wave][0];

    for (int kt = 0; kt < 64; ++kt) {
        __syncthreads();
        {   // stage K tile + V frags + pp (coalesced 16B per thread)
            const uint4 kv = *(const uint4*)(kstage + (size_t)kt * 64 * 768);
            const uint4 vv = *(const uint4*)(vstage + (size_t)kt * 2048);
            *(uint4*)&Klds[t * 8] = kv;
            *(uint4*)&Vlds[t * 8] = vv;
            if (t < 64) pps[t] = ppg[kt * 64];
        }
        __syncthreads();

        // ---- QK^T: 4 subtiles of 16 keys, S^T layout ----
        f32x4 s0, s1, s2, s3;
        {
            const f32x4 z = {0.f, 0.f, 0.f, 0.f};
            const bf16x8 ka0 = *(const bf16x8*)&Klds[(0 * 16 + i16) * 32 + quad * 8];
            const bf16x8 ka1 = *(const bf16x8*)&Klds[(1 * 16 + i16) * 32 + quad * 8];
            const bf16x8 ka2 = *(const bf16x8*)&Klds[(2 * 16 + i16) * 32 + quad * 8];
            const bf16x8 ka3 = *(const bf16x8*)&Klds[(3 * 16 + i16) * 32 + quad * 8];
            s0 = __builtin_amdgcn_mfma_f32_16x16x32_bf16(ka0, qf, z, 0, 0, 0);
            s1 = __builtin_amdgcn_mfma_f32_16x16x32_bf16(ka1, qf, z, 0, 0, 0);
            s2 = __builtin_amdgcn_mfma_f32_16x16x32_bf16(ka2, qf, z, 0, 0, 0);
            s3 = __builtin_amdgcn_mfma_f32_16x16x32_bf16(ka3, qf, z, 0, 0, 0);
        }

        // ---- scores -> exp2 domain with PE bias (key j = s*16+quad*4+r) ----
        float tt[16];
        {
            const float4 pp0 = *(const float4*)&pps[0 * 16 + quad * 4];
            const float4 pp1 = *(const float4*)&pps[1 * 16 + quad * 4];
            const float4 pp2 = *(const float4*)&pps[2 * 16 + quad * 4];
            const float4 pp3 = *(const float4*)&pps[3 * 16 + quad * 4];
#pragma unroll
            for (int r = 0; r < 4; ++r) {
                tt[0 + r]  = fmaf(s0[r], SC2, -((const float*)&pp0)[r]);
                tt[4 + r]  = fmaf(s1[r], SC2, -((const float*)&pp1)[r]);
                tt[8 + r]  = fmaf(s2[r], SC2, -((const float*)&pp2)[r]);
                tt[12 + r] = fmaf(s3[r], SC2, -((const float*)&pp3)[r]);
            }
        }

        // ---- online softmax (per query = per lane&15, reduce over quads) ----
        float tm = tt[0];
#pragma unroll
        for (int j = 1; j < 16; ++j) tm = fmaxf(tm, tt[j]);
        tm = fmaxf(tm, __shfl_xor(tm, 16, 64));
        tm = fmaxf(tm, __shfl_xor(tm, 32, 64));
        const float mnew = fmaxf(m, tm);
        const float alpha = __builtin_amdgcn_exp2f(m - mnew);
        m = mnew;
        l *= alpha;
        o0 *= alpha;
        o1 *= alpha;

        float p[16];
#pragma unroll
        for (int j = 0; j < 16; ++j) {
            p[j] = __builtin_amdgcn_exp2f(tt[j] - mnew);
            l += p[j];
        }

        // ---- pack P -> LDS (P^T rows: [query i16][key j], stride 72) ----
        {
            const int pbase = i16 * 72;
#pragma unroll
            for (int s = 0; s < 4; ++s) {
                bf16x4 pk;
                pk[0] = (bf16)p[s * 4 + 0];
                pk[1] = (bf16)p[s * 4 + 1];
                pk[2] = (bf16)p[s * 4 + 2];
                pk[3] = (bf16)p[s * 4 + 3];
                *(bf16x4*)&ptw[pbase + s * 16 + quad * 4] = pk;
            }
        }
        asm volatile("s_waitcnt lgkmcnt(0)" ::: "memory");

        // ---- PV: O^T += V^T_frag x P^T ----
        {
            const int pbase = i16 * 72;
            const bf16x8 pb0 = *(const bf16x8*)&ptw[pbase + 0 * 32 + quad * 8];
            const bf16x8 pb1 = *(const bf16x8*)&ptw[pbase + 1 * 32 + quad * 8];
            const bf16x8 va00 = *(const bf16x8*)&Vlds[0 * 512 + lane * 8];
            const bf16x8 va01 = *(const bf16x8*)&Vlds[1 * 512 + lane * 8];
            const bf16x8 va10 = *(const bf16x8*)&Vlds[2 * 512 + lane * 8];
            const bf16x8 va11 = *(const bf16x8*)&Vlds[3 * 512 + lane * 8];
            o0 = __builtin_amdgcn_mfma_f32_16x16x32_bf16(va00, pb0, o0, 0, 0, 0);
            o0 = __builtin_amdgcn_mfma_f32_16x16x32_bf16(va01, pb1, o0, 0, 0, 0);
            o1 = __builtin_amdgcn_mfma_f32_16x16x32_bf16(va10, pb0, o1, 0, 0, 0);
            o1 = __builtin_amdgcn_mfma_f32_16x16x32_bf16(va11, pb1, o1, 0, 0, 0);
        }
    }

    // final l across quads; write O (lane holds d=quad*4+r (+16), query=i16)
    l += __shfl_xor(l, 16, 64);
    l += __shfl_xor(l, 32, 64);
    const float inv = 1.0f / l;
    float* outp = attnout + (size_t)(q0w + i16) * 256 + h * 32;
#pragma unroll
    for (int r = 0; r < 4; ++r) {
        outp[quad * 4 + r] = o0[r] * inv;
        outp[16 + quad * 4 + r] = o1[r] * inv;
    }
}

// ---------------------------------------------------------------------------
extern "C" void kernel_launch(void* const* d_in, const int* in_sizes, int n_in,
                              void* d_out, int out_size, void* d_ws, size_t ws_size,
                              hipStream_t stream) {
    const float* x    = (const float*)d_in[0];
    const float* pe   = (const float*)d_in[1];
    const float* Wqkv = (const float*)d_in[2];
    const float* bqkv = (const float*)d_in[3];
    const float* Wpe  = (const float*)d_in[4];
    const float* bpe  = (const float*)d_in[5];
    const float* Wout = (const float*)d_in[6];
    const float* bout = (const float*)d_in[7];
    float* out = (float*)d_out;

    char* ws = (char*)d_ws;
    bf16*  qkvb    = (bf16*)ws;                      // 4096*768 bf16 = 6 MB
    bf16*  vtf     = (bf16*)(ws + 6291456);          // 2 MB frag-order V
    float* ppT     = (float*)(ws + 8388608);         // 128 KB
    float* attnout = (float*)(ws + 8519680);         // 4 MB fp32

    // 1) QKV projection -> bf16
    gemm_k256<768, 3, bf16><<<NN / 8, 256, 0, stream>>>(x, Wqkv, bqkv, qkvb);
    // 2) PE projection (transposed, *log2e)
    pe_proj_kernel<<<(HH * NN) / 256, 256, 0, stream>>>(pe, Wpe, bpe, ppT);
    // 3) V -> A-frag order
    vtrans_kernel<<<dim3(64, HH), 256, 0, stream>>>(qkvb, vtf);
    // 4) MFMA flash attention (PE bias folded)
    attn_kernel<<<dim3(NN / 64, HH), 256, 0, stream>>>(qkvb, vtf, ppT, attnout);
    // 5) Output projection (fp32)
    gemm_k256<256, 1, float><<<NN / 8, 256, 0, stream>>>(attnout, Wout, bout, out);
}

// Round 3
// 150.000 us; speedup vs baseline: 4.0621x; 1.3756x over previous
//
#include <hip/hip_runtime.h>
#include <math.h>

#define NN 4096
#define HH 8
constexpr float SCALE = 0.17677669529663687f;   // 1/sqrt(32)
constexpr float LOG2E = 1.4426950408889634f;
constexpr float SC2   = SCALE * LOG2E;          // folded into Q columns of Wqkv

typedef __bf16 bf16;
typedef __bf16 bf16x8 __attribute__((ext_vector_type(8)));
typedef __bf16 bf16x4 __attribute__((ext_vector_type(4)));
typedef float  f32x4  __attribute__((ext_vector_type(4)));

#define MFMA(a, b, c) __builtin_amdgcn_mfma_f32_16x16x32_bf16((a), (b), (c), 0, 0, 0)

// ---------------------------------------------------------------------------
// x -> hi/lo bf16 split (elementwise)
// ---------------------------------------------------------------------------
__global__ __launch_bounds__(256) void xcast_kernel(const float* __restrict__ x,
                                                    bf16* __restrict__ xh,
                                                    bf16* __restrict__ xl) {
    const int i = (blockIdx.x * 256 + threadIdx.x) * 4;
    const float4 v = *(const float4*)&x[i];
    bf16x4 h, l;
    const float vv[4] = {v.x, v.y, v.z, v.w};
#pragma unroll
    for (int r = 0; r < 4; ++r) {
        h[r] = (bf16)vv[r];
        l[r] = (bf16)(vv[r] - (float)h[r]);
    }
    *(bf16x4*)&xh[i] = h;
    *(bf16x4*)&xl[i] = l;
}

// ---------------------------------------------------------------------------
// W [K][N] fp32 -> W^T hi/lo bf16 [N][K]; optionally scale cols n<256 by SC2
// ---------------------------------------------------------------------------
template <int K, int N, bool SCALEQ>
__global__ __launch_bounds__(256) void wcast_kernel(const float* __restrict__ W,
                                                    bf16* __restrict__ WhT,
                                                    bf16* __restrict__ WlT) {
    __shared__ float tile[64][65];
    const int t = threadIdx.x;
    const int n0 = blockIdx.x * 64, k0 = blockIdx.y * 64;
#pragma unroll
    for (int p = 0; p < 16; ++p) {
        const int r = p * 4 + (t >> 6);
        const int c = t & 63;
        tile[r][c] = W[(size_t)(k0 + r) * N + n0 + c];
    }
    __syncthreads();
    const int nr = t >> 2, kc0 = (t & 3) * 16;
    const float sc = (SCALEQ && (n0 + nr) < 256) ? SC2 : 1.0f;
    bf16x8 h[2], l[2];
#pragma unroll
    for (int g = 0; g < 2; ++g)
#pragma unroll
        for (int j = 0; j < 8; ++j) {
            const float v = tile[kc0 + g * 8 + j][nr] * sc;
            const bf16 hh = (bf16)v;
            h[g][j] = hh;
            l[g][j] = (bf16)(v - (float)hh);
        }
    const size_t ob = (size_t)(n0 + nr) * K + k0 + kc0;
    *(bf16x8*)&WhT[ob] = h[0];
    *(bf16x8*)&WhT[ob + 8] = h[1];
    *(bf16x8*)&WlT[ob] = l[0];
    *(bf16x8*)&WlT[ob + 8] = l[1];
}

__global__ __launch_bounds__(256) void biasscale_kernel(const float* __restrict__ b,
                                                        float* __restrict__ bs) {
    const int i = blockIdx.x * 256 + threadIdx.x; // 768
    bs[i] = b[i] * (i < 256 ? SC2 : 1.0f);
}

// ---------------------------------------------------------------------------
// 3-term split-bf16 GEMM (~fp32 accuracy): C = Ah@Bh^T + Ah@Bl^T + Al@Bh^T + bias
// A: [M][256] bf16 (hi/lo), B^T: [N][256] bf16 (hi/lo). Block 64(M)x64(N).
// Wave w: rows w*16..+15. Frags gathered straight from global (L2-resident).
// ---------------------------------------------------------------------------
template <int NOUT, typename OT>
__global__ __launch_bounds__(256, 2) void gemm3_kernel(const bf16* __restrict__ Ah,
                                                       const bf16* __restrict__ Al,
                                                       const bf16* __restrict__ BhT,
                                                       const bf16* __restrict__ BlT,
                                                       const float* __restrict__ bias,
                                                       OT* __restrict__ C) {
    const int t = threadIdx.x, wave = t >> 6, lane = t & 63;
    const int quad = lane >> 4, i16 = lane & 15;
    const int m0 = blockIdx.x * 64 + wave * 16;
    const int n0 = blockIdx.y * 64;

    bf16x8 ah[8], al[8];
    const size_t abase = (size_t)(m0 + i16) * 256 + quad * 8;
#pragma unroll
    for (int kc = 0; kc < 8; ++kc) {
        ah[kc] = *(const bf16x8*)&Ah[abase + kc * 32];
        al[kc] = *(const bf16x8*)&Al[abase + kc * 32];
    }
#pragma unroll
    for (int ns = 0; ns < 4; ++ns) {
        const int n = n0 + ns * 16 + i16;
        const size_t bbase = (size_t)n * 256 + quad * 8;
        f32x4 acc = {0.f, 0.f, 0.f, 0.f};
#pragma unroll
        for (int kc = 0; kc < 8; ++kc) {
            const bf16x8 bh = *(const bf16x8*)&BhT[bbase + kc * 32];
            const bf16x8 bl = *(const bf16x8*)&BlT[bbase + kc * 32];
            acc = MFMA(ah[kc], bh, acc);
            acc = MFMA(ah[kc], bl, acc);
            acc = MFMA(al[kc], bh, acc);
        }
        const float b = bias[n];
#pragma unroll
        for (int r = 0; r < 4; ++r)
            C[(size_t)(m0 + quad * 4 + r) * NOUT + n] = (OT)(acc[r] + b);
    }
}

// ---------------------------------------------------------------------------
// pe projection -> per-key multiplicative bias in exp2 domain:
// ep[h*N + j] = exp2(-(pe[j]@Wpe[:,h] + bpe[h]) * LOG2E - 8)
// (pp[i] term cancels in softmax; -8 is the fixed flash "m")
// ---------------------------------------------------------------------------
__global__ __launch_bounds__(256) void pe_proj_kernel(const float* __restrict__ pe,
                                                      const float* __restrict__ Wpe,
                                                      const float* __restrict__ bpe,
                                                      float* __restrict__ ep) {
    const int idx = blockIdx.x * 256 + threadIdx.x;
    const int h = idx >> 12;
    const int n = idx & 4095;
    float acc = bpe[h];
#pragma unroll
    for (int k = 0; k < 16; ++k) acc += pe[n * 16 + k] * Wpe[k * 8 + h];
    ep[h * NN + n] = __builtin_amdgcn_exp2f(-acc * LOG2E - 8.0f);
}

// ---------------------------------------------------------------------------
// K and V -> MFMA fragment order. V is pre-scaled by ep[key] and extended with
// an ep-row (dim' 32) so PV-MFMA also produces the softmax denominator l.
// Kf chunk s (s=key/16): lane l holds K[kt*64+s*16+(l&15)][(l>>4)*8+j]
// Vf chunk (dt,kc): lane l holds V''[kc*32+(l>>4)*8+j][dt*16+(l&15)]
//   where V''[key][d<32] = V[key][d]*ep[key]; V''[key][32] = ep[key]; else 0.
// ---------------------------------------------------------------------------
__global__ __launch_bounds__(256) void kvtrans_kernel(const bf16* __restrict__ qkvb,
                                                      const float* __restrict__ ep,
                                                      bf16* __restrict__ Kf,
                                                      bf16* __restrict__ Vf) {
    const int t = threadIdx.x;
    const int kt = blockIdx.x, h = blockIdx.y;
    __shared__ __align__(16) bf16 Ktile[64 * 32];
    __shared__ __align__(16) bf16 Vtile[64 * 32];
    __shared__ float eps[64];
    {
        const int tok = kt * 64 + (t >> 2);
        const int d8 = (t & 3) * 8;
        *(uint4*)&Ktile[(t >> 2) * 32 + d8] =
            *(const uint4*)&qkvb[(size_t)tok * 768 + 256 + h * 32 + d8];
        *(uint4*)&Vtile[(t >> 2) * 32 + d8] =
            *(const uint4*)&qkvb[(size_t)tok * 768 + 512 + h * 32 + d8];
        if (t < 64) eps[t] = ep[h * NN + kt * 64 + t];
    }
    __syncthreads();
    {   // K frags: 4 chunks x 512 bf16
        const int s = t >> 6, l = t & 63, quad = l >> 4, i16 = l & 15;
        bf16x8 o;
#pragma unroll
        for (int j = 0; j < 8; ++j) o[j] = Ktile[(s * 16 + i16) * 32 + quad * 8 + j];
        *(bf16x8*)&Kf[((size_t)(h * 64 + kt) * 4 + s) * 512 + l * 8] = o;
    }
    // V'' frags: 6 chunks x 512 bf16 (3 d-tiles x 2 key-halves)
    for (int c = t; c < 384; c += 256) {
        const int ch = c >> 6, ll = c & 63, qd = ll >> 4, ii = ll & 15;
        const int dt = ch >> 1, kc = ch & 1;
        const int dimp = dt * 16 + ii;
        bf16x8 o;
#pragma unroll
        for (int j = 0; j < 8; ++j) {
            const int key = kc * 32 + qd * 8 + j;
            float v;
            if (dimp < 32)       v = (float)Vtile[key * 32 + dimp] * eps[key];
            else if (dimp == 32) v = eps[key];
            else                 v = 0.f;
            o[j] = (bf16)v;
        }
        *(bf16x8*)&Vf[((size_t)(h * 64 + kt) * 6 + ch) * 512 + ll * 8] = o;
    }
}

// ---------------------------------------------------------------------------
// Fixed-m flash attention, no barriers in main loop, no LDS K/V.
// grid=(64 q-tiles, 8 heads), 4 waves: wave = (qg, kh): 32 queries, 32 key-tiles.
// Per iter: 8 QK MFMA -> 32 exp2 -> P->LDS (wave-private) -> 12 PV MFMA.
// l comes from the V'' ep-row (o[2] row 0). End: merge key-halves via LDS.
// ---------------------------------------------------------------------------
__global__ __launch_bounds__(256, 2) void attn_kernel(const bf16* __restrict__ qkvb,
                                                      const bf16* __restrict__ Kf,
                                                      const bf16* __restrict__ Vf,
                                                      bf16* __restrict__ aoh,
                                                      bf16* __restrict__ aol) {
    const int t = threadIdx.x, wave = t >> 6, lane = t & 63;
    const int quad = lane >> 4, i16 = lane & 15;
    const int qb = blockIdx.x, h = blockIdx.y;
    const int qg = wave & 1, kh = wave >> 1;

    __shared__ __align__(16) bf16 Pt[4][2][16 * 72]; // per-wave P^T, bank-even
    __shared__ __align__(16) float Mrg[2][64][24];   // key-half merge

    const int q0 = qb * 64 + qg * 32;
    const bf16x8 qf0 = *(const bf16x8*)&qkvb[(size_t)(q0 + i16) * 768 + h * 32 + quad * 8];
    const bf16x8 qf1 = *(const bf16x8*)&qkvb[(size_t)(q0 + 16 + i16) * 768 + h * 32 + quad * 8];

    f32x4 o[3][2];
#pragma unroll
    for (int dt = 0; dt < 3; ++dt)
#pragma unroll
        for (int qs = 0; qs < 2; ++qs) o[dt][qs] = f32x4{0.f, 0.f, 0.f, 0.f};

    const bf16* kb = Kf + (size_t)(h * 64) * 2048 + lane * 8;
    const bf16* vb = Vf + (size_t)(h * 64) * 3072 + lane * 8;
    bf16* ptw = &Pt[wave][0][0];

    const int kt0 = kh * 32;
    bf16x8 kcur[4];
#pragma unroll
    for (int s = 0; s < 4; ++s)
        kcur[s] = *(const bf16x8*)&kb[((size_t)kt0 * 4 + s) * 512];

    for (int it = 0; it < 32; ++it) {
        const int kt = kt0 + it;
        // V for current tile (used after softmax -> latency hidden)
        bf16x8 vv[6];
#pragma unroll
        for (int c = 0; c < 6; ++c)
            vv[c] = *(const bf16x8*)&vb[((size_t)kt * 6 + c) * 512];
        // K prefetch for next tile
        bf16x8 knx[4];
        if (it < 31) {
#pragma unroll
            for (int s = 0; s < 4; ++s)
                knx[s] = *(const bf16x8*)&kb[((size_t)(kt + 1) * 4 + s) * 512];
        } else {
#pragma unroll
            for (int s = 0; s < 4; ++s) knx[s] = kcur[s];
        }

        // QK^T: S^T frags, row=key(quad*4+r), col=query(i16). Scores already
        // in exp2 domain (SC2 folded into Wq).
        const f32x4 z = {0.f, 0.f, 0.f, 0.f};
        f32x4 sf[4][2];
#pragma unroll
        for (int ks = 0; ks < 4; ++ks) {
            sf[ks][0] = MFMA(kcur[ks], qf0, z);
            sf[ks][1] = MFMA(kcur[ks], qf1, z);
        }

        // P = exp2(s); bias+fixed-m live in V''. Pack to wave-private LDS.
#pragma unroll
        for (int qs = 0; qs < 2; ++qs)
#pragma unroll
            for (int ks = 0; ks < 4; ++ks) {
                bf16x4 pk;
#pragma unroll
                for (int r = 0; r < 4; ++r)
                    pk[r] = (bf16)__builtin_amdgcn_exp2f(sf[ks][qs][r]);
                *(bf16x4*)&ptw[qs * (16 * 72) + i16 * 72 + ks * 16 + quad * 4] = pk;
            }
        asm volatile("s_waitcnt lgkmcnt(0)" ::: "memory");

        // PV: O^T[dim][query] += V''_frag x P^T  (o[2] row0 accumulates l)
#pragma unroll
        for (int qs = 0; qs < 2; ++qs) {
            const bf16x8 pb0 = *(const bf16x8*)&ptw[qs * (16 * 72) + i16 * 72 + 0 * 32 + quad * 8];
            const bf16x8 pb1 = *(const bf16x8*)&ptw[qs * (16 * 72) + i16 * 72 + 1 * 32 + quad * 8];
#pragma unroll
            for (int dt = 0; dt < 3; ++dt) {
                o[dt][qs] = MFMA(vv[dt * 2 + 0], pb0, o[dt][qs]);
                o[dt][qs] = MFMA(vv[dt * 2 + 1], pb1, o[dt][qs]);
            }
        }
#pragma unroll
        for (int s = 0; s < 4; ++s) kcur[s] = knx[s];
    }

    // merge the two key-halves (fixed m: plain sums), normalize, store hi/lo
    if (kh == 1) {
#pragma unroll
        for (int dt = 0; dt < 3; ++dt)
#pragma unroll
            for (int qs = 0; qs < 2; ++qs)
                *(f32x4*)&Mrg[qg][lane][(dt * 2 + qs) * 4] = o[dt][qs];
    }
    __syncthreads();
    if (kh == 0) {
#pragma unroll
        for (int dt = 0; dt < 3; ++dt)
#pragma unroll
            for (int qs = 0; qs < 2; ++qs)
                o[dt][qs] += *(const f32x4*)&Mrg[qg][lane][(dt * 2 + qs) * 4];
        // l for query col=i16 lives in o[2] row 0 (lanes 0..15, reg 0)
        const float linv0 = 1.0f / __shfl(o[2][0][0], i16, 64);
        const float linv1 = 1.0f / __shfl(o[2][1][0], i16, 64);
#pragma unroll
        for (int qs = 0; qs < 2; ++qs) {
            const float inv = qs ? linv1 : linv0;
            const int row = q0 + qs * 16 + i16;
#pragma unroll
            for (int dt = 0; dt < 2; ++dt) {
                bf16x4 hi, lo;
#pragma unroll
                for (int r = 0; r < 4; ++r) {
                    const float v = o[dt][qs][r] * inv;
                    hi[r] = (bf16)v;
                    lo[r] = (bf16)(v - (float)hi[r]);
                }
                const size_t ob = (size_t)row * 256 + h * 32 + dt * 16 + quad * 4;
                *(bf16x4*)&aoh[ob] = hi;
                *(bf16x4*)&aol[ob] = lo;
            }
        }
    }
}

// ---------------------------------------------------------------------------
extern "C" void kernel_launch(void* const* d_in, const int* in_sizes, int n_in,
                              void* d_out, int out_size, void* d_ws, size_t ws_size,
                              hipStream_t stream) {
    const float* x    = (const float*)d_in[0];
    const float* pe   = (const float*)d_in[1];
    const float* Wqkv = (const float*)d_in[2];
    const float* bqkv = (const float*)d_in[3];
    const float* Wpe  = (const float*)d_in[4];
    const float* bpe  = (const float*)d_in[5];
    const float* Wout = (const float*)d_in[6];
    const float* bout = (const float*)d_in[7];
    float* out = (float*)d_out;

    char* ws = (char*)d_ws;
    bf16*  xh      = (bf16*)(ws);                   // 2 MB
    bf16*  xl      = (bf16*)(ws + 2097152);         // 2 MB
    bf16*  WqkvhT  = (bf16*)(ws + 4194304);         // 384 KB
    bf16*  WqkvlT  = (bf16*)(ws + 4587520);         // 384 KB
    bf16*  WouthT  = (bf16*)(ws + 4980736);         // 128 KB
    bf16*  WoutlT  = (bf16*)(ws + 5111808);         // 128 KB
    float* bqkv_s  = (float*)(ws + 5242880);        // 3 KB
    bf16*  qkvb    = (bf16*)(ws + 5245952);         // 6 MB
    float* ep      = (float*)(ws + 11537408);       // 128 KB
    bf16*  Kf      = (bf16*)(ws + 11668480);        // 2 MB
    bf16*  Vf      = (bf16*)(ws + 13765632);        // 3 MB
    bf16*  aoh     = (bf16*)(ws + 16911360);        // 2 MB
    bf16*  aol     = (bf16*)(ws + 19008512);        // 2 MB -> 21.1 MB total

    xcast_kernel<<<1024, 256, 0, stream>>>(x, xh, xl);
    wcast_kernel<256, 768, true><<<dim3(12, 4), 256, 0, stream>>>(Wqkv, WqkvhT, WqkvlT);
    wcast_kernel<256, 256, false><<<dim3(4, 4), 256, 0, stream>>>(Wout, WouthT, WoutlT);
    biasscale_kernel<<<3, 256, 0, stream>>>(bqkv, bqkv_s);
    pe_proj_kernel<<<128, 256, 0, stream>>>(pe, Wpe, bpe, ep);

    gemm3_kernel<768, bf16><<<dim3(64, 12), 256, 0, stream>>>(xh, xl, WqkvhT, WqkvlT, bqkv_s, qkvb);
    kvtrans_kernel<<<dim3(64, HH), 256, 0, stream>>>(qkvb, ep, Kf, Vf);
    attn_kernel<<<dim3(64, HH), 256, 0, stream>>>(qkvb, Kf, Vf, aoh, aol);
    gemm3_kernel<256, float><<<dim3(64, 4), 256, 0, stream>>>(aoh, aol, WouthT, WoutlT, bout, out);
}

// Round 4
// 146.367 us; speedup vs baseline: 4.1629x; 1.0248x over previous
//
#include <hip/hip_runtime.h>
#include <math.h>

#define NN 4096
#define HH 8
constexpr float SCALE = 0.17677669529663687f;   // 1/sqrt(32)
constexpr float LOG2E = 1.4426950408889634f;
constexpr float SC2   = SCALE * LOG2E;          // folded into Q columns of Wqkv

typedef __bf16 bf16;
typedef __bf16 bf16x8 __attribute__((ext_vector_type(8)));
typedef __bf16 bf16x4 __attribute__((ext_vector_type(4)));
typedef float  f32x4  __attribute__((ext_vector_type(4)));

#define MFMA(a, b, c) __builtin_amdgcn_mfma_f32_16x16x32_bf16((a), (b), (c), 0, 0, 0)

// ---------------------------------------------------------------------------
// W [K][N] fp32 -> W^T hi/lo bf16 [N][K]; optionally scale cols n<256 by SC2.
// device body, called from the fused preproc kernel (uniform per block).
// ---------------------------------------------------------------------------
template <int K, int N, bool SCALEQ>
__device__ __forceinline__ void wcast_body(const float* __restrict__ W,
                                           bf16* __restrict__ WhT,
                                           bf16* __restrict__ WlT,
                                           int n0, int k0, int t,
                                           float (*tile)[65]) {
#pragma unroll
    for (int p = 0; p < 16; ++p) {
        const int r = p * 4 + (t >> 6);
        const int c = t & 63;
        tile[r][c] = W[(size_t)(k0 + r) * N + n0 + c];
    }
    __syncthreads();
    const int nr = t >> 2, kc0 = (t & 3) * 16;
    const float sc = (SCALEQ && (n0 + nr) < 256) ? SC2 : 1.0f;
    bf16x8 h[2], l[2];
#pragma unroll
    for (int g = 0; g < 2; ++g)
#pragma unroll
        for (int j = 0; j < 8; ++j) {
            const float v = tile[kc0 + g * 8 + j][nr] * sc;
            const bf16 hh = (bf16)v;
            h[g][j] = hh;
            l[g][j] = (bf16)(v - (float)hh);
        }
    const size_t ob = (size_t)(n0 + nr) * K + k0 + kc0;
    *(bf16x8*)&WhT[ob] = h[0];
    *(bf16x8*)&WhT[ob + 8] = h[1];
    *(bf16x8*)&WlT[ob] = l[0];
    *(bf16x8*)&WlT[ob + 8] = l[1];
}

// ---------------------------------------------------------------------------
// Fused preprocessing: block-range dispatch over 5 independent jobs.
//  [0,1024)     xcast: x -> hi/lo bf16
//  [1024,1072)  wcast Wqkv (12 x 4 tiles, Q cols pre-scaled by SC2)
//  [1072,1088)  wcast Wout (4 x 4 tiles)
//  [1088,1216)  pe_proj -> ep = exp2(-(pe@Wpe+bpe)*log2e - 8)   (mult. bias)
//  [1216]       bqkv scale (Q rows by SC2)
// ---------------------------------------------------------------------------
__global__ __launch_bounds__(256) void preproc_kernel(
    const float* __restrict__ x, const float* __restrict__ Wqkv,
    const float* __restrict__ Wout, const float* __restrict__ bqkv,
    const float* __restrict__ pe, const float* __restrict__ Wpe,
    const float* __restrict__ bpe,
    bf16* __restrict__ xh, bf16* __restrict__ xl,
    bf16* __restrict__ WqkvhT, bf16* __restrict__ WqkvlT,
    bf16* __restrict__ WouthT, bf16* __restrict__ WoutlT,
    float* __restrict__ bqkv_s, float* __restrict__ ep) {
    __shared__ float tile[64][65];
    const int b = blockIdx.x, t = threadIdx.x;
    if (b < 1024) {
        const int i = (b * 256 + t) * 4;
        const float4 v = *(const float4*)&x[i];
        bf16x4 h, l;
        const float vv[4] = {v.x, v.y, v.z, v.w};
#pragma unroll
        for (int r = 0; r < 4; ++r) {
            h[r] = (bf16)vv[r];
            l[r] = (bf16)(vv[r] - (float)h[r]);
        }
        *(bf16x4*)&xh[i] = h;
        *(bf16x4*)&xl[i] = l;
    } else if (b < 1072) {
        const int bb = b - 1024;
        wcast_body<256, 768, true>(Wqkv, WqkvhT, WqkvlT, (bb % 12) * 64, (bb / 12) * 64, t, tile);
    } else if (b < 1088) {
        const int bb = b - 1072;
        wcast_body<256, 256, false>(Wout, WouthT, WoutlT, (bb % 4) * 64, (bb / 4) * 64, t, tile);
    } else if (b < 1216) {
        const int idx = (b - 1088) * 256 + t;
        const int h = idx >> 12;
        const int n = idx & 4095;
        float acc = bpe[h];
#pragma unroll
        for (int k = 0; k < 16; ++k) acc += pe[n * 16 + k] * Wpe[k * 8 + h];
        ep[h * NN + n] = __builtin_amdgcn_exp2f(-acc * LOG2E - 8.0f);
    } else {
        for (int i = t; i < 768; i += 256)
            bqkv_s[i] = bqkv[i] * (i < 256 ? SC2 : 1.0f);
    }
}

// ---------------------------------------------------------------------------
// 3-term split-bf16 GEMM (~fp32 accuracy): C = Ah@Bh^T + Ah@Bl^T + Al@Bh^T + bias
// ---------------------------------------------------------------------------
template <int NOUT, typename OT>
__global__ __launch_bounds__(256, 2) void gemm3_kernel(const bf16* __restrict__ Ah,
                                                       const bf16* __restrict__ Al,
                                                       const bf16* __restrict__ BhT,
                                                       const bf16* __restrict__ BlT,
                                                       const float* __restrict__ bias,
                                                       OT* __restrict__ C) {
    const int t = threadIdx.x, wave = t >> 6, lane = t & 63;
    const int quad = lane >> 4, i16 = lane & 15;
    const int m0 = blockIdx.x * 64 + wave * 16;
    const int n0 = blockIdx.y * 64;

    bf16x8 ah[8], al[8];
    const size_t abase = (size_t)(m0 + i16) * 256 + quad * 8;
#pragma unroll
    for (int kc = 0; kc < 8; ++kc) {
        ah[kc] = *(const bf16x8*)&Ah[abase + kc * 32];
        al[kc] = *(const bf16x8*)&Al[abase + kc * 32];
    }
#pragma unroll
    for (int ns = 0; ns < 4; ++ns) {
        const int n = n0 + ns * 16 + i16;
        const size_t bbase = (size_t)n * 256 + quad * 8;
        f32x4 acc = {0.f, 0.f, 0.f, 0.f};
#pragma unroll
        for (int kc = 0; kc < 8; ++kc) {
            const bf16x8 bh = *(const bf16x8*)&BhT[bbase + kc * 32];
            const bf16x8 bl = *(const bf16x8*)&BlT[bbase + kc * 32];
            acc = MFMA(ah[kc], bh, acc);
            acc = MFMA(ah[kc], bl, acc);
            acc = MFMA(al[kc], bh, acc);
        }
        const float b = bias[n];
#pragma unroll
        for (int r = 0; r < 4; ++r)
            C[(size_t)(m0 + quad * 4 + r) * NOUT + n] = (OT)(acc[r] + b);
    }
}

// ---------------------------------------------------------------------------
// K and V -> MFMA fragment order; V pre-scaled by ep[key], extended with an
// ep-row so PV-MFMA also produces the softmax denominator l.
// grid (h, kt) so XCD == h (producer lines land on consumer's L2).
// ---------------------------------------------------------------------------
__global__ __launch_bounds__(256) void kvtrans_kernel(const bf16* __restrict__ qkvb,
                                                      const float* __restrict__ ep,
                                                      bf16* __restrict__ Kf,
                                                      bf16* __restrict__ Vf) {
    const int t = threadIdx.x;
    const int kt = blockIdx.y, h = blockIdx.x;
    __shared__ __align__(16) bf16 Ktile[64 * 32];
    __shared__ __align__(16) bf16 Vtile[64 * 32];
    __shared__ float eps[64];
    {
        const int tok = kt * 64 + (t >> 2);
        const int d8 = (t & 3) * 8;
        *(uint4*)&Ktile[(t >> 2) * 32 + d8] =
            *(const uint4*)&qkvb[(size_t)tok * 768 + 256 + h * 32 + d8];
        *(uint4*)&Vtile[(t >> 2) * 32 + d8] =
            *(const uint4*)&qkvb[(size_t)tok * 768 + 512 + h * 32 + d8];
        if (t < 64) eps[t] = ep[h * NN + kt * 64 + t];
    }
    __syncthreads();
    {   // K frags: 4 chunks x 512 bf16
        const int s = t >> 6, l = t & 63, quad = l >> 4, i16 = l & 15;
        bf16x8 o;
#pragma unroll
        for (int j = 0; j < 8; ++j) o[j] = Ktile[(s * 16 + i16) * 32 + quad * 8 + j];
        *(bf16x8*)&Kf[((size_t)(h * 64 + kt) * 4 + s) * 512 + l * 8] = o;
    }
    // V'' frags: 6 chunks x 512 bf16 (3 d-tiles x 2 key-halves)
    for (int c = t; c < 384; c += 256) {
        const int ch = c >> 6, ll = c & 63, qd = ll >> 4, ii = ll & 15;
        const int dt = ch >> 1, kc = ch & 1;
        const int dimp = dt * 16 + ii;
        bf16x8 o;
#pragma unroll
        for (int j = 0; j < 8; ++j) {
            const int key = kc * 32 + qd * 8 + j;
            float v;
            if (dimp < 32)       v = (float)Vtile[key * 32 + dimp] * eps[key];
            else if (dimp == 32) v = eps[key];
            else                 v = 0.f;
            o[j] = (bf16)v;
        }
        *(bf16x8*)&Vf[((size_t)(h * 64 + kt) * 6 + ch) * 512 + ll * 8] = o;
    }
}

// ---------------------------------------------------------------------------
// Fixed-m flash attention, no barriers in main loop, no LDS K/V.
// grid (h, qb) so XCD == h: each XCD's L2 caches exactly one head's Kf+Vf.
// ---------------------------------------------------------------------------
__global__ __launch_bounds__(256, 2) void attn_kernel(const bf16* __restrict__ qkvb,
                                                      const bf16* __restrict__ Kf,
                                                      const bf16* __restrict__ Vf,
                                                      bf16* __restrict__ aoh,
                                                      bf16* __restrict__ aol) {
    const int t = threadIdx.x, wave = t >> 6, lane = t & 63;
    const int quad = lane >> 4, i16 = lane & 15;
    const int qb = blockIdx.y, h = blockIdx.x;
    const int qg = wave & 1, kh = wave >> 1;

    __shared__ __align__(16) bf16 Pt[4][2][16 * 72]; // per-wave P^T, bank-even
    __shared__ __align__(16) float Mrg[2][64][24];   // key-half merge

    const int q0 = qb * 64 + qg * 32;
    const bf16x8 qf0 = *(const bf16x8*)&qkvb[(size_t)(q0 + i16) * 768 + h * 32 + quad * 8];
    const bf16x8 qf1 = *(const bf16x8*)&qkvb[(size_t)(q0 + 16 + i16) * 768 + h * 32 + quad * 8];

    f32x4 o[3][2];
#pragma unroll
    for (int dt = 0; dt < 3; ++dt)
#pragma unroll
        for (int qs = 0; qs < 2; ++qs) o[dt][qs] = f32x4{0.f, 0.f, 0.f, 0.f};

    const bf16* kb = Kf + (size_t)(h * 64) * 2048 + lane * 8;
    const bf16* vb = Vf + (size_t)(h * 64) * 3072 + lane * 8;
    bf16* ptw = &Pt[wave][0][0];

    const int kt0 = kh * 32;
    bf16x8 kcur[4];
#pragma unroll
    for (int s = 0; s < 4; ++s)
        kcur[s] = *(const bf16x8*)&kb[((size_t)kt0 * 4 + s) * 512];

    for (int it = 0; it < 32; ++it) {
        const int kt = kt0 + it;
        bf16x8 vv[6];
#pragma unroll
        for (int c = 0; c < 6; ++c)
            vv[c] = *(const bf16x8*)&vb[((size_t)kt * 6 + c) * 512];
        bf16x8 knx[4];
        if (it < 31) {
#pragma unroll
            for (int s = 0; s < 4; ++s)
                knx[s] = *(const bf16x8*)&kb[((size_t)(kt + 1) * 4 + s) * 512];
        } else {
#pragma unroll
            for (int s = 0; s < 4; ++s) knx[s] = kcur[s];
        }

        const f32x4 z = {0.f, 0.f, 0.f, 0.f};
        f32x4 sf[4][2];
#pragma unroll
        for (int ks = 0; ks < 4; ++ks) {
            sf[ks][0] = MFMA(kcur[ks], qf0, z);
            sf[ks][1] = MFMA(kcur[ks], qf1, z);
        }

#pragma unroll
        for (int qs = 0; qs < 2; ++qs)
#pragma unroll
            for (int ks = 0; ks < 4; ++ks) {
                bf16x4 pk;
#pragma unroll
                for (int r = 0; r < 4; ++r)
                    pk[r] = (bf16)__builtin_amdgcn_exp2f(sf[ks][qs][r]);
                *(bf16x4*)&ptw[qs * (16 * 72) + i16 * 72 + ks * 16 + quad * 4] = pk;
            }
        asm volatile("s_waitcnt lgkmcnt(0)" ::: "memory");

#pragma unroll
        for (int qs = 0; qs < 2; ++qs) {
            const bf16x8 pb0 = *(const bf16x8*)&ptw[qs * (16 * 72) + i16 * 72 + 0 * 32 + quad * 8];
            const bf16x8 pb1 = *(const bf16x8*)&ptw[qs * (16 * 72) + i16 * 72 + 1 * 32 + quad * 8];
#pragma unroll
            for (int dt = 0; dt < 3; ++dt) {
                o[dt][qs] = MFMA(vv[dt * 2 + 0], pb0, o[dt][qs]);
                o[dt][qs] = MFMA(vv[dt * 2 + 1], pb1, o[dt][qs]);
            }
        }
#pragma unroll
        for (int s = 0; s < 4; ++s) kcur[s] = knx[s];
    }

    if (kh == 1) {
#pragma unroll
        for (int dt = 0; dt < 3; ++dt)
#pragma unroll
            for (int qs = 0; qs < 2; ++qs)
                *(f32x4*)&Mrg[qg][lane][(dt * 2 + qs) * 4] = o[dt][qs];
    }
    __syncthreads();
    if (kh == 0) {
#pragma unroll
        for (int dt = 0; dt < 3; ++dt)
#pragma unroll
            for (int qs = 0; qs < 2; ++qs)
                o[dt][qs] += *(const f32x4*)&Mrg[qg][lane][(dt * 2 + qs) * 4];
        const float linv0 = 1.0f / __shfl(o[2][0][0], i16, 64);
        const float linv1 = 1.0f / __shfl(o[2][1][0], i16, 64);
#pragma unroll
        for (int qs = 0; qs < 2; ++qs) {
            const float inv = qs ? linv1 : linv0;
            const int row = q0 + qs * 16 + i16;
#pragma unroll
            for (int dt = 0; dt < 2; ++dt) {
                bf16x4 hi, lo;
#pragma unroll
                for (int r = 0; r < 4; ++r) {
                    const float v = o[dt][qs][r] * inv;
                    hi[r] = (bf16)v;
                    lo[r] = (bf16)(v - (float)hi[r]);
                }
                const size_t ob = (size_t)row * 256 + h * 32 + dt * 16 + quad * 4;
                *(bf16x4*)&aoh[ob] = hi;
                *(bf16x4*)&aol[ob] = lo;
            }
        }
    }
}

// ---------------------------------------------------------------------------
extern "C" void kernel_launch(void* const* d_in, const int* in_sizes, int n_in,
                              void* d_out, int out_size, void* d_ws, size_t ws_size,
                              hipStream_t stream) {
    const float* x    = (const float*)d_in[0];
    const float* pe   = (const float*)d_in[1];
    const float* Wqkv = (const float*)d_in[2];
    const float* bqkv = (const float*)d_in[3];
    const float* Wpe  = (const float*)d_in[4];
    const float* bpe  = (const float*)d_in[5];
    const float* Wout = (const float*)d_in[6];
    const float* bout = (const float*)d_in[7];
    float* out = (float*)d_out;

    char* ws = (char*)d_ws;
    bf16*  xh      = (bf16*)(ws);                   // 2 MB
    bf16*  xl      = (bf16*)(ws + 2097152);         // 2 MB
    bf16*  WqkvhT  = (bf16*)(ws + 4194304);         // 384 KB
    bf16*  WqkvlT  = (bf16*)(ws + 4587520);         // 384 KB
    bf16*  WouthT  = (bf16*)(ws + 4980736);         // 128 KB
    bf16*  WoutlT  = (bf16*)(ws + 5111808);         // 128 KB
    float* bqkv_s  = (float*)(ws + 5242880);        // 3 KB
    bf16*  qkvb    = (bf16*)(ws + 5245952);         // 6 MB
    float* ep      = (float*)(ws + 11537408);       // 128 KB
    bf16*  Kf      = (bf16*)(ws + 11668480);        // 2 MB
    bf16*  Vf      = (bf16*)(ws + 13765632);        // 3 MB
    bf16*  aoh     = (bf16*)(ws + 16911360);        // 2 MB
    bf16*  aol     = (bf16*)(ws + 19008512);        // 2 MB -> 21.1 MB total

    preproc_kernel<<<1217, 256, 0, stream>>>(x, Wqkv, Wout, bqkv, pe, Wpe, bpe,
                                             xh, xl, WqkvhT, WqkvlT, WouthT, WoutlT,
                                             bqkv_s, ep);
    gemm3_kernel<768, bf16><<<dim3(64, 12), 256, 0, stream>>>(xh, xl, WqkvhT, WqkvlT, bqkv_s, qkvb);
    kvtrans_kernel<<<dim3(HH, 64), 256, 0, stream>>>(qkvb, ep, Kf, Vf);
    attn_kernel<<<dim3(HH, NN / 64), 256, 0, stream>>>(qkvb, Kf, Vf, aoh, aol);
    gemm3_kernel<256, float><<<dim3(64, 4), 256, 0, stream>>>(aoh, aol, WouthT, WoutlT, bout, out);
}